// Round 1
// baseline (98017.993 us; speedup 1.0000x reference)
//
#include <hip/hip_runtime.h>
#include <math.h>

#define BATCH  65536
#define SD     256      // STATE_DIM
#define AD     129      // ACTION_DIM
#define HID    256
#define NSTEP  30
#define EPS_LN 1e-5f

#define RPB    32       // rows per block (4 waves x 8 rows)
#define HSTR   260      // h_lds row stride (dwords): 16B-aligned rows, (4r+k)%32 banks -> conflict-free
#define XSTR   132      // x_lds row stride
#define W3STR  132      // padded W3 stride in d_ws

// Repack W3 (256x129 row-major) -> W3p (256x132, zero-padded) so each lane's
// 16-col chunk is float4-aligned. Runs every call (d_ws is re-poisoned).
__global__ __launch_bounds__(256)
void repack_w3(const float* __restrict__ W3, float* __restrict__ W3p) {
    int idx = blockIdx.x * 256 + threadIdx.x;
    if (idx < HID * W3STR) {
        int k = idx / W3STR;
        int j = idx - k * W3STR;
        W3p[idx] = (j < AD) ? W3[k * AD + j] : 0.0f;
    }
}

__global__ __launch_bounds__(256, 3)
void actor_kernel(const float* __restrict__ state,
                  const float* __restrict__ amask,
                  const float* __restrict__ x_init,
                  const float* __restrict__ gum,
                  const float* __restrict__ W1,
                  const float* __restrict__ b1,
                  const float* __restrict__ g1,
                  const float* __restrict__ be1,
                  const float* __restrict__ W2,
                  const float* __restrict__ b2,
                  const float* __restrict__ g2,
                  const float* __restrict__ be2,
                  const float* __restrict__ W3p,
                  const float* __restrict__ b3,
                  float* __restrict__ out)
{
    __shared__ float h_lds[RPB][HSTR];
    __shared__ float x_lds[RPB][XSTR];

    const int tid = threadIdx.x;
    const int r   = tid >> 3;      // row within block, 0..31
    const int g   = tid & 7;       // octet lane, 0..7
    const int row = blockIdx.x * RPB + r;
    const int jb  = 32 * g;        // hidden-col base for this lane

    float* hrow = h_lds[r];
    float* xrow = x_lds[r];

    // ---- stage x_init into LDS ----
    #pragma unroll
    for (int i = 0; i < 17; ++i) {
        int j = g + 8 * i;
        if (j < AD) xrow[j] = x_init[row * AD + j];
    }
    // ---- stage state into h_lds (reused as layer input for the pre pass) ----
    {
        const float4* s4 = (const float4*)(state + (size_t)row * SD + jb);
        #pragma unroll
        for (int q = 0; q < 8; ++q) ((float4*)(hrow + jb))[q] = s4[q];
    }

    float pre[32], acc[32];
    {
        const float4* b14 = (const float4*)(b1 + jb);
        #pragma unroll
        for (int q = 0; q < 8; ++q) ((float4*)pre)[q] = b14[q];
    }
    __syncthreads();

    // ---- pre = b1 + state @ W1[0:256,:]  (once; state never changes) ----
    #pragma unroll 2
    for (int k = 0; k < SD; ++k) {
        float hk = hrow[k];
        const float4* w4 = (const float4*)(W1 + (size_t)k * HID + jb);
        #pragma unroll
        for (int q = 0; q < 8; ++q) {
            float4 w = w4[q];
            pre[4*q+0] = fmaf(hk, w.x, pre[4*q+0]);
            pre[4*q+1] = fmaf(hk, w.y, pre[4*q+1]);
            pre[4*q+2] = fmaf(hk, w.z, pre[4*q+2]);
            pre[4*q+3] = fmaf(hk, w.w, pre[4*q+3]);
        }
    }

    const float* W1x = W1 + (size_t)SD * HID;    // rows 256..384 (x part)
    const float* W1t = W1 + (size_t)385 * HID;   // row 385 (t column)

    // LayerNorm(+ReLU) over this row's 256 accs (8 lanes x 32) -> h_lds
    auto ln_relu_store = [&](const float* __restrict__ gamma,
                             const float* __restrict__ beta) {
        float ssum = 0.f;
        #pragma unroll
        for (int j = 0; j < 32; ++j) ssum += acc[j];
        ssum += __shfl_xor(ssum, 1);
        ssum += __shfl_xor(ssum, 2);
        ssum += __shfl_xor(ssum, 4);
        float mean = ssum * (1.0f / 256.0f);
        float vsum = 0.f;
        #pragma unroll
        for (int j = 0; j < 32; ++j) { float d = acc[j] - mean; vsum = fmaf(d, d, vsum); }
        vsum += __shfl_xor(vsum, 1);
        vsum += __shfl_xor(vsum, 2);
        vsum += __shfl_xor(vsum, 4);
        float rs = rsqrtf(vsum * (1.0f / 256.0f) + EPS_LN);
        const float4* g4 = (const float4*)(gamma + jb);
        const float4* b4 = (const float4*)(beta + jb);
        #pragma unroll
        for (int q = 0; q < 8; ++q) {
            float4 gv = g4[q], bv = b4[q];
            float4 h;
            h.x = fmaxf((acc[4*q+0] - mean) * rs * gv.x + bv.x, 0.f);
            h.y = fmaxf((acc[4*q+1] - mean) * rs * gv.y + bv.y, 0.f);
            h.z = fmaxf((acc[4*q+2] - mean) * rs * gv.z + bv.z, 0.f);
            h.w = fmaxf((acc[4*q+3] - mean) * rs * gv.w + bv.w, 0.f);
            ((float4*)(hrow + jb))[q] = h;
        }
    };

    for (int s = 0; s < NSTEP; ++s) {
        const float t = (float)(NSTEP - 1 - s);

        // ---- layer 1: acc = pre + t*W1t + x @ W1x ----
        {
            const float4* wt4 = (const float4*)(W1t + jb);
            #pragma unroll
            for (int q = 0; q < 8; ++q) {
                float4 w = wt4[q];
                acc[4*q+0] = fmaf(t, w.x, pre[4*q+0]);
                acc[4*q+1] = fmaf(t, w.y, pre[4*q+1]);
                acc[4*q+2] = fmaf(t, w.z, pre[4*q+2]);
                acc[4*q+3] = fmaf(t, w.w, pre[4*q+3]);
            }
        }
        #pragma unroll 2
        for (int k = 0; k < AD; ++k) {
            float xk = xrow[k];
            const float4* w4 = (const float4*)(W1x + (size_t)k * HID + jb);
            #pragma unroll
            for (int q = 0; q < 8; ++q) {
                float4 w = w4[q];
                acc[4*q+0] = fmaf(xk, w.x, acc[4*q+0]);
                acc[4*q+1] = fmaf(xk, w.y, acc[4*q+1]);
                acc[4*q+2] = fmaf(xk, w.z, acc[4*q+2]);
                acc[4*q+3] = fmaf(xk, w.w, acc[4*q+3]);
            }
        }
        __syncthreads();                 // prior readers of h_lds are done
        ln_relu_store(g1, be1);
        __syncthreads();                 // h1 visible

        // ---- layer 2: acc = b2 + h1 @ W2 ----
        {
            const float4* b24 = (const float4*)(b2 + jb);
            #pragma unroll
            for (int q = 0; q < 8; ++q) ((float4*)acc)[q] = b24[q];
        }
        #pragma unroll 2
        for (int k = 0; k < HID; ++k) {
            float hk = hrow[k];
            const float4* w4 = (const float4*)(W2 + (size_t)k * HID + jb);
            #pragma unroll
            for (int q = 0; q < 8; ++q) {
                float4 w = w4[q];
                acc[4*q+0] = fmaf(hk, w.x, acc[4*q+0]);
                acc[4*q+1] = fmaf(hk, w.y, acc[4*q+1]);
                acc[4*q+2] = fmaf(hk, w.z, acc[4*q+2]);
                acc[4*q+3] = fmaf(hk, w.w, acc[4*q+3]);
            }
        }
        __syncthreads();                 // h1 readers done
        ln_relu_store(g2, be2);
        __syncthreads();                 // h2 visible

        // ---- layer 3: noise_pred (lane owns cols 16g..16g+15; col 128 on g==7) ----
        float a3[17];
        #pragma unroll
        for (int i = 0; i < 16; ++i) a3[i] = b3[16 * g + i];
        a3[16] = b3[128];                // uniform; only g==7's result is used
        #pragma unroll 2
        for (int k = 0; k < HID; ++k) {
            float hk = hrow[k];
            const float* wr = W3p + k * W3STR;
            const float4* w4 = (const float4*)(wr + 16 * g);
            #pragma unroll
            for (int q = 0; q < 4; ++q) {
                float4 w = w4[q];
                a3[4*q+0] = fmaf(hk, w.x, a3[4*q+0]);
                a3[4*q+1] = fmaf(hk, w.y, a3[4*q+1]);
                a3[4*q+2] = fmaf(hk, w.z, a3[4*q+2]);
                a3[4*q+3] = fmaf(hk, w.w, a3[4*q+3]);
            }
            a3[16] = fmaf(hk, wr[128], a3[16]);  // uniform scalar-path load
        }
        // ---- x -= 0.1*noise_pred  (safe: all L1 x-reads finished before LN1 sync) ----
        #pragma unroll
        for (int i = 0; i < 16; ++i) {
            int j = 16 * g + i;
            xrow[j] = xrow[j] - 0.1f * a3[i];
        }
        if (g == 7) xrow[128] = xrow[128] - 0.1f * a3[16];
        __syncthreads();                 // x visible for next step's layer 1
    }

    // ---- finale: masked gumbel softmax -> straight-through one-hot, tanh(step) ----
    {
        const int jb3 = 16 * g;
        const float4* m4 = (const float4*)(amask + (size_t)row * 128 + jb3);
        const float4* g4 = (const float4*)(gum   + (size_t)row * 128 + jb3);
        float lg[16];
        #pragma unroll
        for (int q = 0; q < 4; ++q) {
            float4 mv = m4[q], gv = g4[q];
            lg[4*q+0] = xrow[jb3+4*q+0] + (1.f - mv.x) * (-1e9f) + gv.x;
            lg[4*q+1] = xrow[jb3+4*q+1] + (1.f - mv.y) * (-1e9f) + gv.y;
            lg[4*q+2] = xrow[jb3+4*q+2] + (1.f - mv.z) * (-1e9f) + gv.z;
            lg[4*q+3] = xrow[jb3+4*q+3] + (1.f - mv.w) * (-1e9f) + gv.w;
        }
        float lmax = lg[0];
        #pragma unroll
        for (int i = 1; i < 16; ++i) lmax = fmaxf(lmax, lg[i]);
        lmax = fmaxf(lmax, __shfl_xor(lmax, 1));
        lmax = fmaxf(lmax, __shfl_xor(lmax, 2));
        lmax = fmaxf(lmax, __shfl_xor(lmax, 4));
        float es[16];
        float esum = 0.f;
        #pragma unroll
        for (int i = 0; i < 16; ++i) { es[i] = expf(lg[i] - lmax); esum += es[i]; }
        esum += __shfl_xor(esum, 1);
        esum += __shfl_xor(esum, 2);
        esum += __shfl_xor(esum, 4);
        float soft[16];
        float smax = 0.f;
        #pragma unroll
        for (int i = 0; i < 16; ++i) { soft[i] = es[i] / esum; smax = fmaxf(smax, soft[i]); }
        smax = fmaxf(smax, __shfl_xor(smax, 1));
        smax = fmaxf(smax, __shfl_xor(smax, 2));
        smax = fmaxf(smax, __shfl_xor(smax, 4));
        // first index achieving the max (matches jnp.argmax tie-breaking)
        int lidx = 0x7fffffff;
        #pragma unroll
        for (int i = 0; i < 16; ++i) {
            if (soft[i] == smax && lidx == 0x7fffffff) lidx = jb3 + i;
        }
        lidx = min(lidx, __shfl_xor(lidx, 1));
        lidx = min(lidx, __shfl_xor(lidx, 2));
        lidx = min(lidx, __shfl_xor(lidx, 4));
        float* orow = out + (size_t)row * AD;
        #pragma unroll
        for (int i = 0; i < 16; ++i) {
            int j = jb3 + i;
            float hard = (j == lidx) ? 1.0f : 0.0f;
            orow[j] = hard + soft[i] - soft[i];   // straight-through, as written in ref
        }
        if (g == 7) orow[128] = tanhf(xrow[128]);
    }
}

extern "C" void kernel_launch(void* const* d_in, const int* in_sizes, int n_in,
                              void* d_out, int out_size, void* d_ws, size_t ws_size,
                              hipStream_t stream) {
    const float* state  = (const float*)d_in[0];
    const float* amask  = (const float*)d_in[1];
    const float* x_init = (const float*)d_in[2];
    const float* gum    = (const float*)d_in[3];
    const float* W1     = (const float*)d_in[4];
    const float* b1     = (const float*)d_in[5];
    const float* g1     = (const float*)d_in[6];
    const float* be1    = (const float*)d_in[7];
    const float* W2     = (const float*)d_in[8];
    const float* b2     = (const float*)d_in[9];
    const float* g2     = (const float*)d_in[10];
    const float* be2    = (const float*)d_in[11];
    const float* W3     = (const float*)d_in[12];
    const float* b3     = (const float*)d_in[13];
    float* out = (float*)d_out;
    float* W3p = (float*)d_ws;    // 256*132*4 = 135168 bytes

    hipLaunchKernelGGL(repack_w3, dim3((HID * W3STR + 255) / 256), dim3(256), 0, stream,
                       W3, W3p);
    hipLaunchKernelGGL(actor_kernel, dim3(BATCH / RPB), dim3(256), 0, stream,
                       state, amask, x_init, gum, W1, b1, g1, be1,
                       W2, b2, g2, be2, W3p, b3, out);
}